// Round 1
// baseline (740.108 us; speedup 1.0000x reference)
//
#include <hip/hip_runtime.h>

// SparseRoiExtraCut: ordered stream-compaction of is_inside (512 x 200000 bool)
// -> flat indices (row-major order, first max_selected), then gather
//    ext_coords = [coords[ci].xyz, box] and features[ci].
//
// Pipeline (all on `stream`):
//   1. init_flag      : flag=0
//   2. detect_mode    : probe first 256KB; nonzero byte at pos%4==1 => 1-byte bools
//   3. count_kernel   : per-block nonzero counts (2048 blocks x 50000 elems)
//   4. scan_kernel    : exclusive scan of 2048 counts + total (1 block)
//   5. compact_kernel : order-preserving compaction (wave shfl prefix + LDS)
//   6. gather_kernel  : float4 gather of coords/features, zero-fill invalid rows

#define NB 2048   // compaction blocks
#define BS 256    // threads per block (4 waves)

__device__ __forceinline__ int cb4(unsigned w){
  return (int)((w & 0x000000ffu)!=0) + (int)((w & 0x0000ff00u)!=0) +
         (int)((w & 0x00ff0000u)!=0) + (int)((w & 0xff000000u)!=0);
}

__global__ void init_flag(int* flag){ *flag = 0; }

// If bools are 1 byte: bytes at global pos%4==1 are nonzero with p~0.002.
// If bools are int32 (0/1) or float32 (0/1.0f): byte at pos%4==1 is always 0.
__global__ void detect_mode(const uchar4* p, int nvec, int* flag){
  int found = 0;
  for (int i = blockIdx.x*blockDim.x + threadIdx.x; i < nvec;
       i += gridDim.x*blockDim.x){
    uchar4 v = p[i];          // covers bytes 4i..4i+3 ; .y is pos%4==1
    if (v.y) found = 1;
  }
  if (found) atomicOr(flag, 1);
}

__global__ void count_kernel(const uint4* data, const int* flag,
                             long long totalElems, int epb, int* counts){
  const bool byteMode = (*flag != 0);
  const int tid = threadIdx.x;
  const long long elemBase = (long long)blockIdx.x * (long long)epb;
  int cnt = 0;
  if (byteMode){
    const int nvec = epb >> 4;               // 16 elems per uint4
    const uint4* base = data + (elemBase >> 4);
    for (int v = tid; v < nvec; v += BS){
      if (elemBase + ((long long)v << 4) >= totalElems) break;
      uint4 x = base[v];
      cnt += cb4(x.x)+cb4(x.y)+cb4(x.z)+cb4(x.w);
    }
  } else {
    const int nvec = epb >> 2;               // 4 elems per uint4
    const uint4* base = data + (elemBase >> 2);
    for (int v = tid; v < nvec; v += BS){
      if (elemBase + ((long long)v << 2) >= totalElems) break;
      uint4 x = base[v];
      cnt += (int)(x.x!=0)+(int)(x.y!=0)+(int)(x.z!=0)+(int)(x.w!=0);
    }
  }
  const int lane = tid & 63, wid = tid >> 6;
  for (int off = 32; off > 0; off >>= 1) cnt += __shfl_down(cnt, off, 64);
  __shared__ int wsum[BS/64];
  if (lane == 0) wsum[wid] = cnt;
  __syncthreads();
  if (tid == 0){
    int s = 0;
    for (int w = 0; w < BS/64; ++w) s += wsum[w];
    counts[blockIdx.x] = s;
  }
}

__global__ void scan_kernel(const int* counts, int* offsets, int* totalOut, int nb){
  const int tid = threadIdx.x;
  const int per = (nb + BS - 1)/BS;          // 8 for nb=2048
  const int base = tid*per;
  int vals[16];                              // local exclusive prefixes
  int sum = 0;
  for (int k = 0; k < per; ++k){
    int idx = base + k;
    int c = (idx < nb) ? counts[idx] : 0;
    vals[k] = sum; sum += c;
  }
  int incl = sum;
  const int lane = tid & 63, wid = tid >> 6;
  for (int off = 1; off < 64; off <<= 1){
    int t = __shfl_up(incl, off, 64);
    if (lane >= off) incl += t;
  }
  __shared__ int wsum[BS/64];
  if (lane == 63) wsum[wid] = incl;
  __syncthreads();
  int wbase = 0;
  for (int w = 0; w < wid; ++w) wbase += wsum[w];
  const int excl = wbase + incl - sum;       // exclusive prefix of this thread's chunk
  for (int k = 0; k < per; ++k){
    int idx = base + k;
    if (idx < nb) offsets[idx] = excl + vals[k];
  }
  if (tid == BS-1){
    int t = 0;
    for (int w = 0; w < BS/64; ++w) t += wsum[w];
    *totalOut = t;
  }
}

__global__ void compact_kernel(const uint4* data, const int* flag, const int* offsets,
                               long long totalElems, int epb, int max_sel, int* outIdx){
  const bool byteMode = (*flag != 0);
  const int tid = threadIdx.x;
  const int lane = tid & 63, wid = tid >> 6;
  const long long elemBase = (long long)blockIdx.x * (long long)epb;
  int running = offsets[blockIdx.x];
  __shared__ int wsum[BS/64];

  if (byteMode){
    const int nvec = epb >> 4;
    const uint4* base = data + (elemBase >> 4);
    const int iters = (nvec + BS - 1)/BS;
    for (int it = 0; it < iters; ++it){
      const int v = it*BS + tid;
      uint4 x = make_uint4(0u,0u,0u,0u);
      const bool active = (v < nvec) &&
                          (elemBase + ((long long)v << 4) < totalElems);
      if (active) x = base[v];
      const int cnt = cb4(x.x)+cb4(x.y)+cb4(x.z)+cb4(x.w);
      // wave-level inclusive scan
      int incl = cnt;
      for (int off = 1; off < 64; off <<= 1){
        int t = __shfl_up(incl, off, 64);
        if (lane >= off) incl += t;
      }
      if (lane == 63) wsum[wid] = incl;
      __syncthreads();
      int wbase = 0;
      for (int w = 0; w < wid; ++w) wbase += wsum[w];
      int iterTotal = 0;
      for (int w = 0; w < BS/64; ++w) iterTotal += wsum[w];
      int pos = running + wbase + incl - cnt;
      if (cnt){
        const long long e0 = elemBase + ((long long)v << 4);
        unsigned words[4] = {x.x, x.y, x.z, x.w};
        #pragma unroll
        for (int wI = 0; wI < 4; ++wI){
          unsigned w = words[wI];
          #pragma unroll
          for (int b = 0; b < 4; ++b){
            if ((w >> (8*b)) & 0xffu){
              if (pos < max_sel) outIdx[pos] = (int)(e0 + wI*4 + b);
              ++pos;
            }
          }
        }
      }
      running += iterTotal;
      __syncthreads();
    }
  } else {
    const int nvec = epb >> 2;
    const uint4* base = data + (elemBase >> 2);
    const int iters = (nvec + BS - 1)/BS;
    for (int it = 0; it < iters; ++it){
      const int v = it*BS + tid;
      uint4 x = make_uint4(0u,0u,0u,0u);
      const bool active = (v < nvec) &&
                          (elemBase + ((long long)v << 2) < totalElems);
      if (active) x = base[v];
      const int cnt = (int)(x.x!=0)+(int)(x.y!=0)+(int)(x.z!=0)+(int)(x.w!=0);
      int incl = cnt;
      for (int off = 1; off < 64; off <<= 1){
        int t = __shfl_up(incl, off, 64);
        if (lane >= off) incl += t;
      }
      if (lane == 63) wsum[wid] = incl;
      __syncthreads();
      int wbase = 0;
      for (int w = 0; w < wid; ++w) wbase += wsum[w];
      int iterTotal = 0;
      for (int w = 0; w < BS/64; ++w) iterTotal += wsum[w];
      int pos = running + wbase + incl - cnt;
      if (cnt){
        const long long e0 = elemBase + ((long long)v << 2);
        unsigned words[4] = {x.x, x.y, x.z, x.w};
        #pragma unroll
        for (int j = 0; j < 4; ++j){
          if (words[j]){
            if (pos < max_sel) outIdx[pos] = (int)(e0 + j);
            ++pos;
          }
        }
      }
      running += iterTotal;
      __syncthreads();
    }
  }
}

__global__ void gather_kernel(const int* selIdx, const int* totalPtr,
                              const int4* coords, const float4* feat,
                              int num_coords, int c4, int max_sel,
                              float4* outExt, float4* outFeat){
  const int lane = threadIdx.x & 31;
  const int rowsPerBlock = blockDim.x >> 5;
  const int r = blockIdx.x*rowsPerBlock + (threadIdx.x >> 5);
  if (r >= max_sel) return;
  int total = *totalPtr;
  if (total > max_sel) total = max_sel;
  if (r < total){
    const int flat = selIdx[r];
    const unsigned box = (unsigned)flat / (unsigned)num_coords;
    const int ci = flat - (int)box*num_coords;
    const float4* src = feat + (long long)ci*c4;
    float4* dst = outFeat + (long long)r*c4;
    for (int c = lane; c < c4; c += 32) dst[c] = src[c];
    if (lane == 0){
      int4 cc = coords[ci];
      outExt[r] = make_float4((float)cc.x, (float)cc.y, (float)cc.z, (float)box);
    }
  } else {
    const float4 z = make_float4(0.f, 0.f, 0.f, 0.f);
    float4* dst = outFeat + (long long)r*c4;
    for (int c = lane; c < c4; c += 32) dst[c] = z;
    if (lane == 0) outExt[r] = z;
  }
}

extern "C" void kernel_launch(void* const* d_in, const int* in_sizes, int n_in,
                              void* d_out, int out_size, void* d_ws, size_t ws_size,
                              hipStream_t stream){
  const int*   coords   = (const int*)d_in[0];
  const float* features = (const float*)d_in[1];
  const void*  inside   = d_in[2];

  const int num_coords = in_sizes[0] / 4;            // 200000
  const int C          = in_sizes[1] / num_coords;   // 128
  const int c4         = C / 4;                      // 32
  const long long totalElems = (long long)in_sizes[2]; // 102,400,000
  const int max_sel    = out_size / (4 + C);         // 262144

  int* ws      = (int*)d_ws;
  int* flag    = ws;
  int* total   = ws + 1;
  int* counts  = ws + 2;
  int* offsets = ws + 2 + NB;
  int* selIdx  = ws + 2 + 2*NB;

  int epb = (int)((totalElems + NB - 1) / NB);
  epb = (epb + 15) & ~15;                            // 50000 (mult of 16)

  hipLaunchKernelGGL(init_flag, dim3(1), dim3(1), 0, stream, flag);
  hipLaunchKernelGGL(detect_mode, dim3(32), dim3(BS), 0, stream,
                     (const uchar4*)inside, 65536 /*256KB*/, flag);
  hipLaunchKernelGGL(count_kernel, dim3(NB), dim3(BS), 0, stream,
                     (const uint4*)inside, flag, totalElems, epb, counts);
  hipLaunchKernelGGL(scan_kernel, dim3(1), dim3(BS), 0, stream,
                     counts, offsets, total, NB);
  hipLaunchKernelGGL(compact_kernel, dim3(NB), dim3(BS), 0, stream,
                     (const uint4*)inside, flag, offsets, totalElems, epb,
                     max_sel, selIdx);
  const int rowsPerBlock = BS / 32;
  const int gblocks = (max_sel + rowsPerBlock - 1) / rowsPerBlock;
  hipLaunchKernelGGL(gather_kernel, dim3(gblocks), dim3(BS), 0, stream,
                     selIdx, total, (const int4*)coords, (const float4*)features,
                     num_coords, c4, max_sel,
                     (float4*)d_out,
                     (float4*)((float*)d_out + (long long)max_sel*4));
}

// Round 2
// 670.689 us; speedup vs baseline: 1.1035x; 1.1035x over previous
//
#include <hip/hip_runtime.h>

// SparseRoiExtraCut v2: bitpack-based ordered stream-compaction.
//   1. detect_mode : probe first 256KB; nonzero byte at pos%4==1 => 1-byte bools
//   2. pack_count  : bools -> 32-bit masks (12.8 MB) + per-block popcount sums
//   3. scan_kernel : exclusive scan of 3125 block counts (+ total)
//   4. emit_kernel : bitmask -> ordered flat indices (selIdx)
//   5. gather_kernel: float4 gather of coords/features, zero-fill invalid rows

#define BS  256    // threads per block (4 waves)
#define WPB 1024   // 32-bit mask words per pack/emit block (32768 bools)
#define DETB 32    // detect blocks

// bit i of result = (byte i of v) != 0, for the 4 bytes of v
__device__ __forceinline__ unsigned nzmask4(unsigned v){
  unsigned t = (v | ((v & 0x7f7f7f7fu) + 0x7f7f7f7fu)) & 0x80808080u;
  return ((t >> 7) & 1u) | ((t >> 14) & 2u) | ((t >> 21) & 4u) | ((t >> 28) & 8u);
}
__device__ __forceinline__ unsigned nzmask16(uint4 x){
  return nzmask4(x.x) | (nzmask4(x.y) << 4) | (nzmask4(x.z) << 8) | (nzmask4(x.w) << 12);
}

// One flag per block, always written => no separate init kernel needed.
__global__ void detect_mode(const uchar4* p, int nvec, int* flags){
  int found = 0;
  for (int i = blockIdx.x*blockDim.x + threadIdx.x; i < nvec;
       i += gridDim.x*blockDim.x){
    uchar4 v = p[i];                 // .y is byte pos%4==1
    if (v.y) found = 1;
  }
  __shared__ int sh;
  if (threadIdx.x == 0) sh = 0;
  __syncthreads();
  if (found) atomicOr(&sh, 1);
  __syncthreads();
  if (threadIdx.x == 0) flags[blockIdx.x] = sh;
}

__global__ void pack_count(const void* data, const int* flags,
                           long long totalElems, int wordsTotal,
                           unsigned* maskOut, int* counts){
  __shared__ int modeSh;
  if (threadIdx.x == 0){
    int f = 0;
    for (int i = 0; i < DETB; ++i) f |= flags[i];
    modeSh = f;
  }
  __syncthreads();
  const bool byteMode = (modeSh != 0);
  const int tid = threadIdx.x;
  int cnt = 0;
  const int wBase = blockIdx.x * WPB;
  if (byteMode){
    const uint4* d = (const uint4*)data;           // 16 bytes per uint4
    const unsigned char* p8 = (const unsigned char*)data;
    for (int i = tid; i < WPB; i += BS){
      const int w = wBase + i;
      if (w >= wordsTotal) break;
      const long long e0 = (long long)w << 5;      // 32 bools per word
      unsigned m;
      if (e0 + 31 < totalElems){
        uint4 a = d[2*w], b = d[2*w+1];
        m = nzmask16(a) | (nzmask16(b) << 16);
      } else {
        m = 0;
        for (int b = 0; b < 32 && e0 + b < totalElems; ++b)
          if (p8[e0 + b]) m |= (1u << b);
      }
      maskOut[w] = m;
      cnt += __popc(m);
    }
  } else {
    const uint4* d = (const uint4*)data;           // 4 elems per uint4
    const unsigned* p32 = (const unsigned*)data;
    for (int i = tid; i < WPB; i += BS){
      const int w = wBase + i;
      if (w >= wordsTotal) break;
      const long long e0 = (long long)w << 5;
      unsigned m = 0;
      if (e0 + 31 < totalElems){
        #pragma unroll
        for (int k = 0; k < 8; ++k){
          uint4 x = d[8*(long long)w + k];
          m |= ((unsigned)(x.x!=0) << (4*k)) | ((unsigned)(x.y!=0) << (4*k+1)) |
               ((unsigned)(x.z!=0) << (4*k+2)) | ((unsigned)(x.w!=0) << (4*k+3));
        }
      } else {
        for (int b = 0; b < 32 && e0 + b < totalElems; ++b)
          if (p32[e0 + b]) m |= (1u << b);
      }
      maskOut[w] = m;
      cnt += __popc(m);
    }
  }
  const int lane = tid & 63, wid = tid >> 6;
  for (int off = 32; off > 0; off >>= 1) cnt += __shfl_down(cnt, off, 64);
  __shared__ int wsum[BS/64];
  if (lane == 0) wsum[wid] = cnt;
  __syncthreads();
  if (tid == 0){
    int s = 0;
    for (int w = 0; w < BS/64; ++w) s += wsum[w];
    counts[blockIdx.x] = s;
  }
}

__global__ void scan_kernel(const int* counts, int* offsets, int* totalOut, int nb){
  const int tid = threadIdx.x;
  const int per = (nb + BS - 1)/BS;               // 13 for nb=3125
  const int base = tid*per;
  int vals[16];
  int sum = 0;
  for (int k = 0; k < per; ++k){
    int idx = base + k;
    int c = (idx < nb) ? counts[idx] : 0;
    vals[k] = sum; sum += c;
  }
  int incl = sum;
  const int lane = tid & 63, wid = tid >> 6;
  for (int off = 1; off < 64; off <<= 1){
    int t = __shfl_up(incl, off, 64);
    if (lane >= off) incl += t;
  }
  __shared__ int wsum[BS/64];
  if (lane == 63) wsum[wid] = incl;
  __syncthreads();
  int wbase = 0;
  for (int w = 0; w < wid; ++w) wbase += wsum[w];
  const int excl = wbase + incl - sum;
  for (int k = 0; k < per; ++k){
    int idx = base + k;
    if (idx < nb) offsets[idx] = excl + vals[k];
  }
  if (tid == BS-1){
    int t = 0;
    for (int w = 0; w < BS/64; ++w) t += wsum[w];
    *totalOut = t;
  }
}

__global__ void emit_kernel(const unsigned* mask, const int* offsets,
                            int wordsTotal, int max_sel, int* outIdx){
  const int tid = threadIdx.x;
  const int lane = tid & 63, wid = tid >> 6;
  const int wBase = blockIdx.x * WPB;
  int running = offsets[blockIdx.x];
  __shared__ int wsum[BS/64];
  const int iters = WPB / BS;                      // 4
  for (int it = 0; it < iters; ++it){
    const int w = wBase + it*BS + tid;
    unsigned m = (w < wordsTotal) ? mask[w] : 0u;
    const int cnt = __popc(m);
    int incl = cnt;
    for (int off = 1; off < 64; off <<= 1){
      int t = __shfl_up(incl, off, 64);
      if (lane >= off) incl += t;
    }
    if (lane == 63) wsum[wid] = incl;
    __syncthreads();
    int wbase = 0;
    for (int ww = 0; ww < wid; ++ww) wbase += wsum[ww];
    int iterTotal = 0;
    for (int ww = 0; ww < BS/64; ++ww) iterTotal += wsum[ww];
    int pos = running + wbase + incl - cnt;
    if (m){
      const long long e0 = (long long)w << 5;
      unsigned mm = m;
      while (mm){
        const int b = __ffs(mm) - 1;
        mm &= mm - 1;
        if (pos < max_sel) outIdx[pos] = (int)(e0 + b);
        ++pos;
      }
    }
    running += iterTotal;
    __syncthreads();
  }
}

__global__ void gather_kernel(const int* selIdx, const int* totalPtr,
                              const int4* coords, const float4* feat,
                              int num_coords, int c4, int max_sel,
                              float4* outExt, float4* outFeat){
  const int lane = threadIdx.x & 31;
  const int rowsPerBlock = blockDim.x >> 5;
  const int r = blockIdx.x*rowsPerBlock + (threadIdx.x >> 5);
  if (r >= max_sel) return;
  int total = *totalPtr;
  if (total > max_sel) total = max_sel;
  if (r < total){
    const int flat = selIdx[r];
    const unsigned box = (unsigned)flat / (unsigned)num_coords;
    const int ci = flat - (int)box*num_coords;
    const float4* src = feat + (long long)ci*c4;
    float4* dst = outFeat + (long long)r*c4;
    for (int c = lane; c < c4; c += 32) dst[c] = src[c];
    if (lane == 0){
      int4 cc = coords[ci];
      outExt[r] = make_float4((float)cc.x, (float)cc.y, (float)cc.z, (float)box);
    }
  } else {
    const float4 z = make_float4(0.f, 0.f, 0.f, 0.f);
    float4* dst = outFeat + (long long)r*c4;
    for (int c = lane; c < c4; c += 32) dst[c] = z;
    if (lane == 0) outExt[r] = z;
  }
}

extern "C" void kernel_launch(void* const* d_in, const int* in_sizes, int n_in,
                              void* d_out, int out_size, void* d_ws, size_t ws_size,
                              hipStream_t stream){
  const int*   coords   = (const int*)d_in[0];
  const float* features = (const float*)d_in[1];
  const void*  inside   = d_in[2];

  const int num_coords = in_sizes[0] / 4;              // 200000
  const int C          = in_sizes[1] / num_coords;     // 128
  const int c4         = C / 4;                        // 32
  const long long totalElems = (long long)in_sizes[2]; // 102,400,000
  const int max_sel    = out_size / (4 + C);           // 262144

  const int wordsTotal = (int)((totalElems + 31) / 32);   // 3,200,000
  const int NBP        = (wordsTotal + WPB - 1) / WPB;    // 3125

  int* ws      = (int*)d_ws;
  int* flags   = ws;                    // DETB
  int* total   = ws + DETB;             // 1
  int* counts  = ws + DETB + 1;         // NBP
  int* offsets = counts + NBP;          // NBP
  int* selIdx  = offsets + NBP;         // max_sel
  unsigned* maskBuf = (unsigned*)(selIdx + max_sel);   // wordsTotal

  hipLaunchKernelGGL(detect_mode, dim3(DETB), dim3(BS), 0, stream,
                     (const uchar4*)inside, 65536 /*256KB*/, flags);
  hipLaunchKernelGGL(pack_count, dim3(NBP), dim3(BS), 0, stream,
                     inside, flags, totalElems, wordsTotal, maskBuf, counts);
  hipLaunchKernelGGL(scan_kernel, dim3(1), dim3(BS), 0, stream,
                     counts, offsets, total, NBP);
  hipLaunchKernelGGL(emit_kernel, dim3(NBP), dim3(BS), 0, stream,
                     maskBuf, offsets, wordsTotal, max_sel, selIdx);
  const int rowsPerBlock = BS / 32;
  const int gblocks = (max_sel + rowsPerBlock - 1) / rowsPerBlock;
  hipLaunchKernelGGL(gather_kernel, dim3(gblocks), dim3(BS), 0, stream,
                     selIdx, total, (const int4*)coords, (const float4*)features,
                     num_coords, c4, max_sel,
                     (float4*)d_out,
                     (float4*)((float*)d_out + (long long)max_sel*4));
}